// Round 1
// 263.628 us; speedup vs baseline: 1.0882x; 1.0882x over previous
//
#include <hip/hip_runtime.h>
#include <hip/hip_bf16.h>

// LocallyConnected2d: y[b,o,h,w] = bias[o,h,w] +
//   sum_{i,kh,kw} xpad[b,i,h+kh,w+kw] * weight[i,o,h,w,kh,kw]
// B=64, CIN=COUT=64, H=W=32, K=3, pad=1, fp32 in/out.
// Round 6 (new session R1): eliminate the af intermediate (75.5 MB write +
// 75.5 MB read) and the im2col_frag kernel. The GEMM kernel builds its A
// fragments per chunk in LDS from xt using the verified scr 2-step transpose
// (each of 8 waves plays producer-quad roles q = 2*nh + s for its own loc).
// Weight prefetch deepened to depth-2 (wa/wb register sets, loop unrolled x2
// so wreg indexing is static). Numerics bit-identical to verified round-5.

#define B_    64
#define HW_   32
#define HP_   34
#define NLOC  1024
#define W_OST 9216u     // floats per o step
#define W_IST 589824u   // floats per i step
#define XT_BYTES  ((size_t)64*HP_*HP_*64*2)          //  9,469,952
#define WS_NEED   (XT_BYTES)

typedef __attribute__((ext_vector_type(8))) short short8;
typedef __attribute__((ext_vector_type(8))) unsigned short ushort8;
typedef __attribute__((ext_vector_type(4))) float floatx4;

static __device__ __forceinline__ unsigned short f2bf(float f) {
  __hip_bfloat16 h = __float2bfloat16(f);   // RNE
  return __builtin_bit_cast(unsigned short, h);
}

// ---------------------------------------------------------------------------
// Kernel 1: pad+transpose x[b][i][h][w] (fp32) -> xt[i][hh][ww][b] (bf16).
// (verified rounds 2-5, unchanged)
// ---------------------------------------------------------------------------
__global__ __launch_bounds__(256) void xpose_pad(const float* __restrict__ x,
                                                 unsigned short* __restrict__ xt) {
  int bid = blockIdx.x;                 // 64*34
  int i = bid / HP_, hh = bid % HP_;
  __shared__ float tile[B_ * 33];
  int t = threadIdx.x;
  bool interior = (hh >= 1 && hh <= HW_);
  if (interior) {
    int h = hh - 1, w = t & 31, bs = t >> 5;
    #pragma unroll
    for (int r = 0; r < 8; ++r) {
      int b = r * 8 + bs;
      tile[b * 33 + w] = x[(((size_t)b * 64 + i) * HW_ + h) * HW_ + w];
    }
  }
  __syncthreads();
  int b = t & 63, wsb = t >> 6;
  size_t base = (size_t)(i * HP_ + hh) * HP_ * B_;
  #pragma unroll
  for (int s = 0; s < 9; ++s) {
    int ww = s * 4 + wsb;
    if (ww < HP_) {
      float v = 0.f;
      if (interior && ww >= 1 && ww <= HW_) v = tile[b * 33 + (ww - 1)];
      xt[base + (size_t)ww * B_ + b] = f2bf(v);
    }
  }
}

// ---------------------------------------------------------------------------
// Kernel 2: fused im2col + weight-transform + GEMM.
// Block = 4 consecutive-w locs, 512 thr = 8 waves: wave = (ll, o-half nh).
// Per chunk c<16 (k' = quad*8+j <-> i = 4c+quad, kk = j):
//   - A side: wave (ll,nh) loads xt ushort8 for q = 2nh+s (s=0,1), scr-
//     transposes (verbatim im2col), writes A-frags to Af[buf^1] (LDS).
//   - B side: stage weight via dense float4 (36-float granules), f2bf +
//     scatter to Bf[buf^1]; kk=8 stashed to Bs for chunks 16/17.
//   - MFMA consumes Af[buf] + Bf[buf].
// Depth-2 weight prefetch: issueW(c+2) each iter, scatterW(c+1) consumes
// loads issued a full chunk earlier.
// ---------------------------------------------------------------------------
__global__ __launch_bounds__(512, 2) void lc2d_fused(
    const unsigned short* __restrict__ xt,
    const float* __restrict__ wsrc,
    const float* __restrict__ bias,
    float* __restrict__ out) {
  __shared__ __align__(16) unsigned short Af[2][4 * 4 * 64 * 8];  // 2 x 16 KB
  __shared__ __align__(16) unsigned short Bf[2][4 * 4 * 64 * 8];  // 2 x 16 KB
  __shared__ __align__(16) unsigned short Bs[4 * 2 * 4 * 64 * 8]; // 32 KB (kk=8)
  __shared__ __align__(16) unsigned short scr[8][512];            // 8 KB

  const int bid  = blockIdx.x;                 // 256 blocks
  const int loc0 = bid << 2;
  const int tid  = threadIdx.x;
  const int lane = tid & 63;
  const int wv8  = tid >> 6;
  const int ll   = wv8 >> 1;                   // wave's loc index 0..3
  const int nh   = wv8 & 1;                    // o-half
  const int loc  = loc0 + ll;
  const int hblk = loc >> 5, wblk = loc & 31;  // 4 locs share h row (loc0%4==0)
  const int col  = lane & 15;
  const int quad = lane >> 4;
  const int o_0  = nh * 32 + col;              // o for nt2=0 (nt2=1 -> +16)

  floatx4 acc[4][2];
  {
    float b0 = bias[(unsigned)o_0 * 1024u + (unsigned)loc];
    float b1 = bias[(unsigned)(o_0 + 16) * 1024u + (unsigned)loc];
    #pragma unroll
    for (int mt = 0; mt < 4; ++mt) {
      acc[mt][0] = (floatx4){b0, b0, b0, b0};
      acc[mt][1] = (floatx4){b1, b1, b1, b1};
    }
  }

  // ---- weight staging: 2304 float4 per chunk (4i x 64o x 36 floats)
  floatx4 wa[5], wb[5];                        // depth-2: two named sets
  const bool lastok = (tid < 256);             // round 4 covers idx 2048..2303
  const size_t wrow = (size_t)loc0 * 9;        // 16B-aligned (loc0 % 4 == 0)

  auto issueW = [&](int c, floatx4 (&wreg)[5]) {
    const int i0 = c << 2;
    #pragma unroll
    for (int r = 0; r < 5; ++r) {
      if (r < 4 || lastok) {
        int idx = r * 512 + tid;
        int g = idx / 9, p = idx - g * 9;      // granule, float4-pos
        int i = i0 + (g >> 6), o = g & 63;
        wreg[r] = *(const floatx4*)(wsrc + (size_t)i * W_IST + (size_t)o * W_OST
                                    + wrow + (size_t)(p * 4));
      }
    }
  };
  auto scatterW = [&](int c, floatx4 (&wreg)[5], unsigned short* bfp) {
    const int i0 = c << 2;
    #pragma unroll
    for (int r = 0; r < 5; ++r) {
      if (r < 4 || lastok) {
        int idx = r * 512 + tid;
        int g = idx / 9, p = idx - g * 9;
        int iq = g >> 6, o = g & 63;
        int ot = o >> 4, oc = o & 15;
        int flane = iq * 16 + oc;              // B-frag lane: quad=iq, col=oc
        #pragma unroll
        for (int e = 0; e < 4; ++e) {
          int fi = p * 4 + e;                  // 0..35 within granule
          int lle = fi / 9, kk = fi - lle * 9;
          unsigned short v = f2bf(wreg[r][e]);
          if (kk < 8) {
            bfp[((lle * 4 + ot) * 64 + flane) * 8 + kk] = v;
          } else {                             // kk == 8 -> stash, k' = i&31
            int i = i0 + iq;
            int sc = i >> 5, k2 = i & 31;
            Bs[((lle * 8 + sc * 4 + ot) * 64 + (k2 >> 3) * 16 + oc) * 8 + (k2 & 7)] = v;
          }
        }
      }
    }
  };

  // ---- A side: xt load + scr transpose -> Af (verbatim im2col mapping,
  //      producer quad role q = 2*nh + s)
  auto xtLoad = [&](int t, int s) -> ushort8 {
    int q = (nh << 1) + s;
    int i, kh, kw;
    if (t < 16) {
      i = (t << 2) + q;
      int kk = lane >> 3;                      // 0..7
      kh = kk / 3; kw = kk - kh * 3;
    } else {
      i = ((t - 16) << 5) + (q << 3) + (lane >> 3);
      kh = 2; kw = 2;
    }
    return *(const ushort8*)(xt +
        (((unsigned)i * HP_ + (unsigned)(hblk + kh)) * HP_ + (unsigned)(wblk + kw)) * 64u
        + ((unsigned)(lane & 7) << 3));
  };
  auto xposeStore = [&](ushort8 v, int s, unsigned short* afp) {
    const int q = (nh << 1) + s;
    *(ushort8*)&scr[wv8][lane << 3] = v;
    __asm__ volatile("s_waitcnt lgkmcnt(0)" ::: "memory");
    ushort8 p;
    #pragma unroll
    for (int jr = 0; jr < 8; ++jr) p[jr] = scr[wv8][jr * 64 + lane];
    __asm__ volatile("s_waitcnt lgkmcnt(0)" ::: "memory");
    *(ushort8*)(afp + (size_t)((((ll << 2) + (lane >> 4)) << 6)
                               + (q << 4) + (lane & 15)) * 8) = p;
  };

  // ---- MFMA: 4 A-frags x 2 B-frags (same call order as verified round 5)
  auto doMFMA = [&](const unsigned short* afp, const unsigned short* bbase, int boff) {
    ushort8 a0 = *(const ushort8*)(afp + (size_t)(((ll << 2) + 0) * 64 + lane) * 8);
    ushort8 a1 = *(const ushort8*)(afp + (size_t)(((ll << 2) + 1) * 64 + lane) * 8);
    ushort8 a2 = *(const ushort8*)(afp + (size_t)(((ll << 2) + 2) * 64 + lane) * 8);
    ushort8 a3 = *(const ushort8*)(afp + (size_t)(((ll << 2) + 3) * 64 + lane) * 8);
    ushort8 b0 = *(const ushort8*)(bbase + (size_t)((boff + 0) * 64 + lane) * 8);
    ushort8 b1 = *(const ushort8*)(bbase + (size_t)((boff + 1) * 64 + lane) * 8);
    acc[0][0] = __builtin_amdgcn_mfma_f32_16x16x32_bf16(
        __builtin_bit_cast(short8, a0), __builtin_bit_cast(short8, b0), acc[0][0], 0, 0, 0);
    acc[1][0] = __builtin_amdgcn_mfma_f32_16x16x32_bf16(
        __builtin_bit_cast(short8, a1), __builtin_bit_cast(short8, b0), acc[1][0], 0, 0, 0);
    acc[2][0] = __builtin_amdgcn_mfma_f32_16x16x32_bf16(
        __builtin_bit_cast(short8, a2), __builtin_bit_cast(short8, b0), acc[2][0], 0, 0, 0);
    acc[3][0] = __builtin_amdgcn_mfma_f32_16x16x32_bf16(
        __builtin_bit_cast(short8, a3), __builtin_bit_cast(short8, b0), acc[3][0], 0, 0, 0);
    acc[0][1] = __builtin_amdgcn_mfma_f32_16x16x32_bf16(
        __builtin_bit_cast(short8, a0), __builtin_bit_cast(short8, b1), acc[0][1], 0, 0, 0);
    acc[1][1] = __builtin_amdgcn_mfma_f32_16x16x32_bf16(
        __builtin_bit_cast(short8, a1), __builtin_bit_cast(short8, b1), acc[1][1], 0, 0, 0);
    acc[2][1] = __builtin_amdgcn_mfma_f32_16x16x32_bf16(
        __builtin_bit_cast(short8, a2), __builtin_bit_cast(short8, b1), acc[2][1], 0, 0, 0);
    acc[3][1] = __builtin_amdgcn_mfma_f32_16x16x32_bf16(
        __builtin_bit_cast(short8, a3), __builtin_bit_cast(short8, b1), acc[3][1], 0, 0, 0);
  };

  // ---- prologue: chunk 0 A+B staged, chunk 1 weights issued
  issueW(0, wa);
  {
    ushort8 pv0 = xtLoad(0, 0);
    ushort8 pv1 = xtLoad(0, 1);
    xposeStore(pv0, 0, &Af[0][0]);
    xposeStore(pv1, 1, &Af[0][0]);
  }
  scatterW(0, wa, &Bf[0][0]);
  issueW(1, wb);
  __syncthreads();

  // ---- main loop c = 0..15 (unrolled x2 so wa/wb indexing is static)
#define STEP(C, WI, WS) do {                                                  \
    const int c_ = (C);                                                       \
    ushort8 xv0 = xtLoad(c_ + 1, 0);                                          \
    ushort8 xv1 = xtLoad(c_ + 1, 1);                                          \
    if (c_ + 2 <= 15) issueW(c_ + 2, WI);                                     \
    doMFMA(&Af[c_ & 1][0], &Bf[c_ & 1][0], (ll << 2) + (nh << 1));            \
    xposeStore(xv0, 0, &Af[(c_ & 1) ^ 1][0]);                                 \
    xposeStore(xv1, 1, &Af[(c_ & 1) ^ 1][0]);                                 \
    if (c_ + 1 <= 15) scatterW(c_ + 1, WS, &Bf[(c_ & 1) ^ 1][0]);             \
    __syncthreads();                                                          \
  } while (0)

  #pragma unroll 1
  for (int cc = 0; cc < 16; cc += 2) {
    STEP(cc,     wa, wb);   // even c: issue->wa, scatter<-wb
    STEP(cc + 1, wb, wa);   // odd  c: issue->wb, scatter<-wa
  }
#undef STEP

  // ---- stash chunks (kk=8): c = 16, 17 (B from Bs; A built in-loop / here)
  {
    ushort8 xv0 = xtLoad(17, 0);
    ushort8 xv1 = xtLoad(17, 1);
    doMFMA(&Af[0][0], &Bs[0], (ll << 3) + 0 + (nh << 1));   // c=16 (sc=0)
    xposeStore(xv0, 0, &Af[1][0]);
    xposeStore(xv1, 1, &Af[1][0]);
    __syncthreads();
    doMFMA(&Af[1][0], &Bs[0], (ll << 3) + 4 + (nh << 1));   // c=17 (sc=1)
  }

  // ---- epilogue: D mapping col=o=lane&15, row=b = mt*16 + quad*4 + r (verified)
  #pragma unroll
  for (int mt = 0; mt < 4; ++mt) {
    int b = mt * 16 + quad * 4;
    #pragma unroll
    for (int r = 0; r < 4; ++r) {
      out[((unsigned)(b + r) * 64u + (unsigned)o_0) * 1024u + (unsigned)loc] = acc[mt][0][r];
      out[((unsigned)(b + r) * 64u + (unsigned)(o_0 + 16)) * 1024u + (unsigned)loc] = acc[mt][1][r];
    }
  }
}

// ---------------------------------------------------------------------------
// Fallback (tiny ws): fp32, direct x reads (round 1, correct for any ws).
// ---------------------------------------------------------------------------
__global__ __launch_bounds__(256, 4) void lc2d_fallback(
    const float* __restrict__ x, const float* __restrict__ weight,
    const float* __restrict__ bias, float* __restrict__ out) {
  int t0 = blockIdx.x;
  int loc = ((t0 & 7) << 7) | (t0 >> 3);
  int h = loc >> 5, w = loc & 31;
  int tid = threadIdx.x;
  int b = tid & 63;
  int o0 = (tid >> 6) * 16;
  __shared__ float As[72 * 64];
  float acc[16];
  #pragma unroll
  for (int j = 0; j < 16; ++j) acc[j] = bias[(size_t)(o0 + j) * NLOC + loc];
  for (int ic = 0; ic < 8; ++ic) {
    __syncthreads();
    #pragma unroll
    for (int s = 0; s < 18; ++s) {
      int f = s * 256 + tid;
      int k = f >> 6, lb = f & 63;
      int kk = k >> 3, isub = k & 7;
      int i = ic * 8 + isub;
      int kh = kk / 3, kw = kk - kh * 3;
      int hh = h + kh - 1, ww = w + kw - 1;
      float v = (hh >= 0 && hh < HW_ && ww >= 0 && ww < HW_)
                  ? x[(((size_t)lb * 64 + i) * HW_ + hh) * HW_ + ww] : 0.f;
      As[k * 64 + lb] = v;
    }
    __syncthreads();
    #pragma unroll 1
    for (int isub = 0; isub < 8; ++isub) {
      const float* wp = weight + (size_t)(ic * 8 + isub) * W_IST
                               + (size_t)o0 * W_OST + loc * 9;
      #pragma unroll
      for (int kk = 0; kk < 9; ++kk) {
        float a = As[(kk * 8 + isub) * 64 + b];
        #pragma unroll
        for (int j = 0; j < 16; ++j)
          acc[j] = fmaf(a, wp[(size_t)j * W_OST + kk], acc[j]);
      }
    }
  }
  size_t ob = ((size_t)b * 64 + o0) * NLOC + loc;
  #pragma unroll
  for (int j = 0; j < 16; ++j) out[ob + (size_t)j * NLOC] = acc[j];
}

// ---------------------------------------------------------------------------
extern "C" void kernel_launch(void* const* d_in, const int* in_sizes, int n_in,
                              void* d_out, int out_size, void* d_ws, size_t ws_size,
                              hipStream_t stream) {
  const float* x  = (const float*)d_in[0];
  const float* wt = (const float*)d_in[1];
  const float* bs = (const float*)d_in[2];
  float* out = (float*)d_out;

  if (ws_size >= WS_NEED) {
    unsigned short* xtb = (unsigned short*)d_ws;
    xpose_pad<<<64 * HP_, 256, 0, stream>>>(x, xtb);
    lc2d_fused<<<NLOC / 4, 512, 0, stream>>>(xtb, wt, bs, out);
  } else {
    lc2d_fallback<<<NLOC, 256, 0, stream>>>(x, wt, bs, out);
  }
}

// Round 2
// 252.183 us; speedup vs baseline: 1.1376x; 1.0454x over previous
//
#include <hip/hip_runtime.h>
#include <hip/hip_bf16.h>

// LocallyConnected2d: y[b,o,h,w] = bias[o,h,w] +
//   sum_{i,kh,kw} xpad[b,i,h+kh,w+kw] * weight[i,o,h,w,kh,kw]
// B=64, CIN=COUT=64, H=W=32, K=3, pad=1, fp32 in/out.
// Round 7: occupancy + XCD locality. Grid 512 blocks x 256 thr (4 waves),
// each block = 4 consecutive locs x ONE o-half (32 o's) -> 2 blocks/CU.
// XCD-grouped swizzle: XCD x owns locs [128x,128x+128) so out lines complete
// in one L2 (kills 4x write amplification) and xt slice (3.3 MB) is
// L2-resident. Soft barrier (lgkmcnt(0)+s_barrier) keeps the depth-2 weight
// prefetch in flight across chunks (no vmcnt(0) drain).
// All round-5/6-verified mappings (scr transpose, scatter, MFMA, epilogue)
// kept parameter-identical.

#define B_    64
#define HW_   32
#define HP_   34
#define NLOC  1024
#define W_OST 9216u     // floats per o step
#define W_IST 589824u   // floats per i step
#define XT_BYTES  ((size_t)64*HP_*HP_*64*2)          //  9,469,952
#define WS_NEED   (XT_BYTES)

typedef __attribute__((ext_vector_type(8))) short short8;
typedef __attribute__((ext_vector_type(8))) unsigned short ushort8;
typedef __attribute__((ext_vector_type(4))) float floatx4;

static __device__ __forceinline__ unsigned short f2bf(float f) {
  __hip_bfloat16 h = __float2bfloat16(f);   // RNE
  return __builtin_bit_cast(unsigned short, h);
}

// soft workgroup barrier: drain LDS only, keep VMEM loads in flight
static __device__ __forceinline__ void soft_barrier() {
  __asm__ volatile("s_waitcnt lgkmcnt(0)" ::: "memory");
  __builtin_amdgcn_s_barrier();
}

// ---------------------------------------------------------------------------
// Kernel 1: pad+transpose x[b][i][h][w] (fp32) -> xt[i][hh][ww][b] (bf16).
// (verified rounds 2-6, unchanged)
// ---------------------------------------------------------------------------
__global__ __launch_bounds__(256) void xpose_pad(const float* __restrict__ x,
                                                 unsigned short* __restrict__ xt) {
  int bid = blockIdx.x;                 // 64*34
  int i = bid / HP_, hh = bid % HP_;
  __shared__ float tile[B_ * 33];
  int t = threadIdx.x;
  bool interior = (hh >= 1 && hh <= HW_);
  if (interior) {
    int h = hh - 1, w = t & 31, bs = t >> 5;
    #pragma unroll
    for (int r = 0; r < 8; ++r) {
      int b = r * 8 + bs;
      tile[b * 33 + w] = x[(((size_t)b * 64 + i) * HW_ + h) * HW_ + w];
    }
  }
  __syncthreads();
  int b = t & 63, wsb = t >> 6;
  size_t base = (size_t)(i * HP_ + hh) * HP_ * B_;
  #pragma unroll
  for (int s = 0; s < 9; ++s) {
    int ww = s * 4 + wsb;
    if (ww < HP_) {
      float v = 0.f;
      if (interior && ww >= 1 && ww <= HW_) v = tile[b * 33 + (ww - 1)];
      xt[base + (size_t)ww * B_ + b] = f2bf(v);
    }
  }
}

// ---------------------------------------------------------------------------
// Kernel 2: fused im2col + weight-transform + GEMM, o-half split.
// Block = 4 consecutive locs x 32 o's, 256 thr = 4 waves; wave = ll (loc).
// Per chunk c<16 (k' = quad*8+j <-> i = 4c+quad, kk = j):
//   A: wave ll builds all 4 producer roles q=0..3 for its loc (scr pairs).
//   B: stage 4i x 32o x 4loc x 9kk via dense float4, f2bf + scatter to
//      Bf[buf^1]; kk=8 stashed to Bs for chunks 16/17.
//   MFMA consumes Af[buf] + Bf[buf]. Depth-2 weight prefetch (wa/wb).
// ---------------------------------------------------------------------------
__global__ __launch_bounds__(256, 2) void lc2d_fused(
    const unsigned short* __restrict__ xt,
    const float* __restrict__ wsrc,
    const float* __restrict__ bias,
    float* __restrict__ out) {
  __shared__ __align__(16) unsigned short Af[2][16 * 64 * 8];  // 2 x 16 KB
  __shared__ __align__(16) unsigned short Bf[2][8 * 64 * 8];   // 2 x 8 KB
  __shared__ __align__(16) unsigned short Bs[16 * 64 * 8];     // 16 KB (kk=8)
  __shared__ __align__(16) unsigned short scr[4][2][512];      // 8 KB

  const int bid   = blockIdx.x;                    // 512 blocks
  const int lt    = ((bid & 7) << 6) | (bid >> 3); // XCD-grouped tile id
  const int ohalf = lt & 1;
  const int loc0  = (lt >> 1) << 2;                // loc0 % 4 == 0
  const int tid   = threadIdx.x;
  const int lane  = tid & 63;
  const int ll    = tid >> 6;                      // wave = loc index 0..3
  const int loc   = loc0 + ll;
  const int hblk  = loc >> 5, wblk = loc & 31;
  const int col   = lane & 15;
  const int quad  = lane >> 4;
  const int o_0   = ohalf * 32 + col;              // nt=0 -> o_0, nt=1 -> +16

  floatx4 acc[4][2];
  {
    float b0 = bias[(unsigned)o_0 * 1024u + (unsigned)loc];
    float b1 = bias[(unsigned)(o_0 + 16) * 1024u + (unsigned)loc];
    #pragma unroll
    for (int mt = 0; mt < 4; ++mt) {
      acc[mt][0] = (floatx4){b0, b0, b0, b0};
      acc[mt][1] = (floatx4){b1, b1, b1, b1};
    }
  }

  // ---- weight staging: 1152 float4 per chunk (4i x 32o x 4loc x 9kk)
  floatx4 wa[5], wb[5];                        // depth-2: two named sets
  const bool lastok = (tid < 128);             // round 4: idx 1024..1151
  const size_t wrow = (size_t)loc0 * 9;        // bytes loc0*36, loc0%4==0 -> 16B-aligned
  const unsigned obase = (unsigned)ohalf * 32u;

  auto issueW = [&](int c, floatx4 (&wreg)[5]) {
    const int i0 = c << 2;
    #pragma unroll
    for (int r = 0; r < 5; ++r) {
      if (r < 4 || lastok) {
        int idx = r * 256 + tid;
        int g = idx / 9, p = idx - g * 9;      // granule, float4-pos
        int i = i0 + (g >> 5), o = (int)obase + (g & 31);
        wreg[r] = *(const floatx4*)(wsrc + (size_t)i * W_IST + (size_t)o * W_OST
                                    + wrow + (size_t)(p * 4));
      }
    }
  };
  auto scatterW = [&](int c, floatx4 (&wreg)[5], unsigned short* bfp) {
    const int i0 = c << 2;
    #pragma unroll
    for (int r = 0; r < 5; ++r) {
      if (r < 4 || lastok) {
        int idx = r * 256 + tid;
        int g = idx / 9, p = idx - g * 9;
        int iq = g >> 5, ol = g & 31;
        int ot = ol >> 4, oc = ol & 15;
        int flane = iq * 16 + oc;              // B-frag lane: quad=iq, col=oc
        #pragma unroll
        for (int e = 0; e < 4; ++e) {
          int fi = p * 4 + e;                  // 0..35 within granule
          int lle = fi / 9, kk = fi - lle * 9;
          unsigned short v = f2bf(wreg[r][e]);
          if (kk < 8) {
            bfp[((lle * 2 + ot) * 64 + flane) * 8 + kk] = v;
          } else {                             // kk == 8 -> stash, k' = i&31
            int i = i0 + iq;
            int sc = i >> 5, k2 = i & 31;
            Bs[(((lle * 2 + sc) * 2 + ot) * 64 + (k2 >> 3) * 16 + oc) * 8 + (k2 & 7)] = v;
          }
        }
      }
    }
  };

  // ---- A side: xt load + scr transpose -> Af (verified mapping, param q)
  auto xtLoad = [&](int t, int q) -> ushort8 {
    int i, kh, kw;
    if (t < 16) {
      i = (t << 2) + q;
      int kk = lane >> 3;                      // 0..7
      kh = kk / 3; kw = kk - kh * 3;
    } else {
      i = ((t - 16) << 5) + (q << 3) + (lane >> 3);
      kh = 2; kw = 2;
    }
    return *(const ushort8*)(xt +
        (((unsigned)i * HP_ + (unsigned)(hblk + kh)) * HP_ + (unsigned)(wblk + kw)) * 64u
        + ((unsigned)(lane & 7) << 3));
  };
  // transpose two producer roles (q0, q0+1) through two scr slots
  auto xposePair = [&](ushort8 v0, ushort8 v1, int q0, unsigned short* afp) {
    *(ushort8*)&scr[ll][0][lane << 3] = v0;
    *(ushort8*)&scr[ll][1][lane << 3] = v1;
    __asm__ volatile("s_waitcnt lgkmcnt(0)" ::: "memory");
    ushort8 p0, p1;
    #pragma unroll
    for (int jr = 0; jr < 8; ++jr) p0[jr] = scr[ll][0][jr * 64 + lane];
    #pragma unroll
    for (int jr = 0; jr < 8; ++jr) p1[jr] = scr[ll][1][jr * 64 + lane];
    __asm__ volatile("s_waitcnt lgkmcnt(0)" ::: "memory");
    *(ushort8*)(afp + (size_t)((((ll << 2) + (lane >> 4)) << 6)
                               + (q0 << 4) + (lane & 15)) * 8) = p0;
    *(ushort8*)(afp + (size_t)((((ll << 2) + (lane >> 4)) << 6)
                               + ((q0 + 1) << 4) + (lane & 15)) * 8) = p1;
  };

  // ---- MFMA: 4 A-frags x 2 B-frags (same call order as verified rounds)
  auto doMFMA = [&](const unsigned short* afp, const unsigned short* bbase, int boff) {
    ushort8 a0 = *(const ushort8*)(afp + (size_t)(((ll << 2) + 0) * 64 + lane) * 8);
    ushort8 a1 = *(const ushort8*)(afp + (size_t)(((ll << 2) + 1) * 64 + lane) * 8);
    ushort8 a2 = *(const ushort8*)(afp + (size_t)(((ll << 2) + 2) * 64 + lane) * 8);
    ushort8 a3 = *(const ushort8*)(afp + (size_t)(((ll << 2) + 3) * 64 + lane) * 8);
    ushort8 b0 = *(const ushort8*)(bbase + (size_t)((boff + 0) * 64 + lane) * 8);
    ushort8 b1 = *(const ushort8*)(bbase + (size_t)((boff + 1) * 64 + lane) * 8);
    acc[0][0] = __builtin_amdgcn_mfma_f32_16x16x32_bf16(
        __builtin_bit_cast(short8, a0), __builtin_bit_cast(short8, b0), acc[0][0], 0, 0, 0);
    acc[1][0] = __builtin_amdgcn_mfma_f32_16x16x32_bf16(
        __builtin_bit_cast(short8, a1), __builtin_bit_cast(short8, b0), acc[1][0], 0, 0, 0);
    acc[2][0] = __builtin_amdgcn_mfma_f32_16x16x32_bf16(
        __builtin_bit_cast(short8, a2), __builtin_bit_cast(short8, b0), acc[2][0], 0, 0, 0);
    acc[3][0] = __builtin_amdgcn_mfma_f32_16x16x32_bf16(
        __builtin_bit_cast(short8, a3), __builtin_bit_cast(short8, b0), acc[3][0], 0, 0, 0);
    acc[0][1] = __builtin_amdgcn_mfma_f32_16x16x32_bf16(
        __builtin_bit_cast(short8, a0), __builtin_bit_cast(short8, b1), acc[0][1], 0, 0, 0);
    acc[1][1] = __builtin_amdgcn_mfma_f32_16x16x32_bf16(
        __builtin_bit_cast(short8, a1), __builtin_bit_cast(short8, b1), acc[1][1], 0, 0, 0);
    acc[2][1] = __builtin_amdgcn_mfma_f32_16x16x32_bf16(
        __builtin_bit_cast(short8, a2), __builtin_bit_cast(short8, b1), acc[2][1], 0, 0, 0);
    acc[3][1] = __builtin_amdgcn_mfma_f32_16x16x32_bf16(
        __builtin_bit_cast(short8, a3), __builtin_bit_cast(short8, b1), acc[3][1], 0, 0, 0);
  };

  // ---- prologue: chunk 0 A+B staged, chunk 1 weights issued
  issueW(0, wa);
  {
    ushort8 v0 = xtLoad(0, 0), v1 = xtLoad(0, 1);
    ushort8 v2 = xtLoad(0, 2), v3 = xtLoad(0, 3);
    xposePair(v0, v1, 0, &Af[0][0]);
    xposePair(v2, v3, 2, &Af[0][0]);
  }
  scatterW(0, wa, &Bf[0][0]);
  issueW(1, wb);
  soft_barrier();

  // ---- main loop c = 0..15 (unrolled x2 so wa/wb indexing is static)
#define STEP(C, WI, WS) do {                                                  \
    const int c_ = (C);                                                       \
    ushort8 xv0 = xtLoad(c_ + 1, 0), xv1 = xtLoad(c_ + 1, 1);                 \
    ushort8 xv2 = xtLoad(c_ + 1, 2), xv3 = xtLoad(c_ + 1, 3);                 \
    if (c_ + 2 <= 15) issueW(c_ + 2, WI);                                     \
    doMFMA(&Af[c_ & 1][0], &Bf[c_ & 1][0], ll << 1);                          \
    xposePair(xv0, xv1, 0, &Af[(c_ & 1) ^ 1][0]);                             \
    xposePair(xv2, xv3, 2, &Af[(c_ & 1) ^ 1][0]);                             \
    if (c_ + 1 <= 15) scatterW(c_ + 1, WS, &Bf[(c_ & 1) ^ 1][0]);             \
    soft_barrier();                                                           \
  } while (0)

  #pragma unroll 1
  for (int cc = 0; cc < 16; cc += 2) {
    STEP(cc,     wa, wb);   // even c: issue->wa, scatter<-wb
    STEP(cc + 1, wb, wa);   // odd  c: issue->wb, scatter<-wa
  }
#undef STEP

  // ---- stash chunks (kk=8): c = 16, 17 (B from Bs)
  {
    ushort8 xv0 = xtLoad(17, 0), xv1 = xtLoad(17, 1);
    ushort8 xv2 = xtLoad(17, 2), xv3 = xtLoad(17, 3);
    doMFMA(&Af[0][0], &Bs[0], (ll << 1) << 1);        // sc=0: boff=(ll*2+0)*2
    xposePair(xv0, xv1, 0, &Af[1][0]);
    xposePair(xv2, xv3, 2, &Af[1][0]);
    soft_barrier();
    doMFMA(&Af[1][0], &Bs[0], ((ll << 1) + 1) << 1);  // sc=1: boff=(ll*2+1)*2
  }

  // ---- epilogue: D mapping col=o=lane&15, row=b = mt*16 + quad*4 + r (verified)
  #pragma unroll
  for (int mt = 0; mt < 4; ++mt) {
    int b = mt * 16 + quad * 4;
    #pragma unroll
    for (int r = 0; r < 4; ++r) {
      out[((unsigned)(b + r) * 64u + (unsigned)o_0) * 1024u + (unsigned)loc] = acc[mt][0][r];
      out[((unsigned)(b + r) * 64u + (unsigned)(o_0 + 16)) * 1024u + (unsigned)loc] = acc[mt][1][r];
    }
  }
}

// ---------------------------------------------------------------------------
// Fallback (tiny ws): fp32, direct x reads (round 1, correct for any ws).
// ---------------------------------------------------------------------------
__global__ __launch_bounds__(256, 4) void lc2d_fallback(
    const float* __restrict__ x, const float* __restrict__ weight,
    const float* __restrict__ bias, float* __restrict__ out) {
  int t0 = blockIdx.x;
  int loc = ((t0 & 7) << 7) | (t0 >> 3);
  int h = loc >> 5, w = loc & 31;
  int tid = threadIdx.x;
  int b = tid & 63;
  int o0 = (tid >> 6) * 16;
  __shared__ float As[72 * 64];
  float acc[16];
  #pragma unroll
  for (int j = 0; j < 16; ++j) acc[j] = bias[(size_t)(o0 + j) * NLOC + loc];
  for (int ic = 0; ic < 8; ++ic) {
    __syncthreads();
    #pragma unroll
    for (int s = 0; s < 18; ++s) {
      int f = s * 256 + tid;
      int k = f >> 6, lb = f & 63;
      int kk = k >> 3, isub = k & 7;
      int i = ic * 8 + isub;
      int kh = kk / 3, kw = kk - kh * 3;
      int hh = h + kh - 1, ww = w + kw - 1;
      float v = (hh >= 0 && hh < HW_ && ww >= 0 && ww < HW_)
                  ? x[(((size_t)lb * 64 + i) * HW_ + hh) * HW_ + ww] : 0.f;
      As[k * 64 + lb] = v;
    }
    __syncthreads();
    #pragma unroll 1
    for (int isub = 0; isub < 8; ++isub) {
      const float* wp = weight + (size_t)(ic * 8 + isub) * W_IST
                               + (size_t)o0 * W_OST + loc * 9;
      #pragma unroll
      for (int kk = 0; kk < 9; ++kk) {
        float a = As[(kk * 8 + isub) * 64 + b];
        #pragma unroll
        for (int j = 0; j < 16; ++j)
          acc[j] = fmaf(a, wp[(size_t)j * W_OST + kk], acc[j]);
      }
    }
  }
  size_t ob = ((size_t)b * 64 + o0) * NLOC + loc;
  #pragma unroll
  for (int j = 0; j < 16; ++j) out[ob + (size_t)j * NLOC] = acc[j];
}

// ---------------------------------------------------------------------------
extern "C" void kernel_launch(void* const* d_in, const int* in_sizes, int n_in,
                              void* d_out, int out_size, void* d_ws, size_t ws_size,
                              hipStream_t stream) {
  const float* x  = (const float*)d_in[0];
  const float* wt = (const float*)d_in[1];
  const float* bs = (const float*)d_in[2];
  float* out = (float*)d_out;

  if (ws_size >= WS_NEED) {
    unsigned short* xtb = (unsigned short*)d_ws;
    xpose_pad<<<64 * HP_, 256, 0, stream>>>(x, xtb);
    lc2d_fused<<<512, 256, 0, stream>>>(xtb, wt, bs, out);
  } else {
    lc2d_fallback<<<NLOC, 256, 0, stream>>>(x, wt, bs, out);
  }
}